// Round 15
// baseline (645.762 us; speedup 1.0000x reference)
//
#include <hip/hip_runtime.h>

#define HID 50
#define FOURH 200
#define TSTEPS 2048
#define NBATCH 1024

#define LOG2E 1.44269504f

typedef _Float16 v2h __attribute__((ext_vector_type(2)));

__device__ __forceinline__ float frcp(float x)  { return __builtin_amdgcn_rcpf(x); }
__device__ __forceinline__ float fexp2(float x) { return __builtin_amdgcn_exp2f(x); }
__device__ __forceinline__ v2h bc_v2h(unsigned int u) {
    return __builtin_bit_cast(v2h, u);
}

// FINAL / champion structure (r12, 640us). Issue model v3, validated over 9
// kernels: lone wave (1/SIMD, pinned by batch=1024) issues 1 VALU inst / 4cy;
// dur = plain*4 + trans*16 + ~45cy step-boundary stall. Per-step floor:
// 100 fdot2 (400cy) + 25 readlane+pkrtz+DPP (108cy) + 5 exp2 + 2 rcp (112cy)
// + ~20 plain tail (80cy) ~= 700cy ~= 600us; this kernel measures 750cy.
// Alternatives all measured worse: MFMA (r3 +38%), 2-wave split (r5/r6
// +53-64%), int8 dot4 (r8 accuracy-fail 1.3e-3 > 9.5e-4), LDS h-broadcast
// (r13 +80cy stall), rcp-merge/pk-pairs (r14, net-neutral by op count).
//  - h broadcast: DPP row_shl:1 (f32) + cvt_pkrtz pack + 25 v_readlane ->
//    SGPR operands for fdot2 (VOP3P reads 1 SGPR), no LDS on the h path.
//  - single 25-dot chain per gate, init = fmaf(xt, wx, b).
//  - scales folded: i/f/o weights * -L (sigmoid sign), g * +2L (tanh form);
//    cell kept in 2L-space.
//  - two-rcp tail: prod = 2L(eg-1)/[(1+ei)(1+eg)], fg = rcp(1+ef),
//    h = (ec-1)/[(1+eo)(1+ec)].
//  - x via float4 LDS read / 4 steps, prefetched one block ahead.
__global__ __launch_bounds__(64, 1)
void lstm_trans_kernel(const float* __restrict__ x,
                       const float* __restrict__ Wx,
                       const float* __restrict__ Wh,
                       const float* __restrict__ bias,
                       const float* __restrict__ Wd,
                       const float* __restrict__ bd,
                       float* __restrict__ out) {
    const int b    = blockIdx.x;
    const int lane = threadIdx.x;
    const int lc   = (lane < HID) ? lane : (HID - 1);

    __shared__ __align__(16) float xs[TSTEPS + 8];

    // Stage x (coalesced float4 loads).
    const float4* xb4 = (const float4*)(x + (size_t)b * TSTEPS);
    float4* xs4 = (float4*)xs;
    #pragma unroll
    for (int i = lane; i < TSTEPS / 4; i += 64) xs4[i] = xb4[i];
    if (lane < 8) xs[TSTEPS + lane] = 0.0f;

    // Recurrent weights packed along k as half2 (25 pairs), scales folded:
    // i/f/o -> -L (sigmoid sign), g -> +2L (tanh form).
    const float SNEG = -LOG2E;
    const float S2L  = 2.0f * LOG2E;
    v2h wi[25], wf[25], wg[25], wo[25];
    #pragma unroll
    for (int k2 = 0; k2 < 25; ++k2) {
        const float* r0 = Wh + (2 * k2) * FOURH;
        const float* r1 = Wh + (2 * k2 + 1) * FOURH;
        wi[k2] = v2h{(_Float16)(SNEG * r0[lc]),           (_Float16)(SNEG * r1[lc])};
        wf[k2] = v2h{(_Float16)(SNEG * r0[HID + lc]),     (_Float16)(SNEG * r1[HID + lc])};
        wg[k2] = v2h{(_Float16)(S2L  * r0[2 * HID + lc]), (_Float16)(S2L  * r1[2 * HID + lc])};
        wo[k2] = v2h{(_Float16)(SNEG * r0[3 * HID + lc]), (_Float16)(SNEG * r1[3 * HID + lc])};
    }
    const float wx_i = SNEG * Wx[lc],           b_i = SNEG * bias[lc];
    const float wx_f = SNEG * Wx[HID + lc],     b_f = SNEG * bias[HID + lc];
    const float wx_g = S2L  * Wx[2 * HID + lc], b_g = S2L  * bias[2 * HID + lc];
    const float wx_o = SNEG * Wx[3 * HID + lc], b_o = SNEG * bias[3 * HID + lc];

    float cs = 0.0f;   // 2L-scaled cell state
    float h  = 0.0f;
    __syncthreads();   // x staging visible

    const float4* xsv = (const float4*)xs;
    float4 xq = xsv[0];

    for (int tb = 0; tb < TSTEPS; tb += 4) {
        const float4 xq_next = xsv[(tb >> 2) + 1];   // prefetch next block

        #pragma unroll
        for (int s = 0; s < 4; ++s) {
            const float xt = (s == 0) ? xq.x : (s == 1) ? xq.y
                           : (s == 2) ? xq.z : xq.w;

            // --- h broadcast: DPP neighbor (f32) -> cvt_pkrtz pack -> 25 readlane.
            const int hi32 = __builtin_bit_cast(int, h);
            const int hn32 = __builtin_amdgcn_update_dpp(
                0, hi32, 0x101 /*row_shl:1*/, 0xf, 0xf, true);
            const float hn = __builtin_bit_cast(float, hn32);
            const unsigned hp =
                __builtin_bit_cast(unsigned, __builtin_amdgcn_cvt_pkrtz(h, hn));
            unsigned sh[25];
            #pragma unroll
            for (int k = 0; k < 25; ++k)
                sh[k] = (unsigned)__builtin_amdgcn_readlane((int)hp, 2 * k);

            // --- 4 single dot chains (25 fdot2 each), init = x-path + bias.
            float zi = fmaf(xt, wx_i, b_i);
            #pragma unroll
            for (int j = 0; j < 25; ++j)
                zi = __builtin_amdgcn_fdot2(wi[j], bc_v2h(sh[j]), zi, false);
            const float ei = fexp2(zi);                 // e^{-z_i}

            float zg = fmaf(xt, wx_g, b_g);
            #pragma unroll
            for (int j = 0; j < 25; ++j)
                zg = __builtin_amdgcn_fdot2(wg[j], bc_v2h(sh[j]), zg, false);
            const float eg = fexp2(zg);                 // e^{2 z_g}

            // prod = ig*gg2L = 2L(eg-1) / [(1+ei)(1+eg)]  (one rcp for both)
            const float den1 = (1.0f + ei) * (1.0f + eg);
            const float r1   = frcp(den1);
            const float num1 = fmaf(eg, S2L, -S2L);     // 2L*(eg-1)
            const float prod = num1 * r1;

            float zf = fmaf(xt, wx_f, b_f);
            #pragma unroll
            for (int j = 0; j < 25; ++j)
                zf = __builtin_amdgcn_fdot2(wf[j], bc_v2h(sh[j]), zf, false);
            const float ef = fexp2(zf);                 // e^{-z_f}
            const float fg = frcp(1.0f + ef);

            const float cs_new = fmaf(fg, cs, prod);    // 2L * c
            const float ec = fexp2(cs_new);             // e^{2c} (under o-dots)

            float zo = fmaf(xt, wx_o, b_o);
            #pragma unroll
            for (int j = 0; j < 25; ++j)
                zo = __builtin_amdgcn_fdot2(wo[j], bc_v2h(sh[j]), zo, false);
            const float eo = fexp2(zo);                 // e^{-z_o}

            // h = og * tanh(c) = (ec-1) / [(1+eo)(1+ec)]  (one rcp for both)
            const float den2 = (1.0f + eo) * (1.0f + ec);
            const float r2   = frcp(den2);
            const float num2 = ec - 1.0f;
            cs = cs_new;
            h  = num2 * r2;
        }

        xq = xq_next;
    }

    // out[b] = h_T . Wd + bd
    float v = (lane < HID) ? h * Wd[lane] : 0.0f;
    #pragma unroll
    for (int off = 32; off > 0; off >>= 1) v += __shfl_down(v, off);
    if (lane == 0) out[b] = v + bd[0];
}

extern "C" void kernel_launch(void* const* d_in, const int* in_sizes, int n_in,
                              void* d_out, int out_size, void* d_ws, size_t ws_size,
                              hipStream_t stream) {
    const float* x    = (const float*)d_in[0];  // [1024, 2048, 1]
    const float* Wx   = (const float*)d_in[1];  // [1, 200]
    const float* Wh   = (const float*)d_in[2];  // [50, 200]
    const float* bias = (const float*)d_in[3];  // [200]
    const float* Wd   = (const float*)d_in[4];  // [50, 1]
    const float* bd   = (const float*)d_in[5];  // [1]
    float* out = (float*)d_out;                 // [1024, 1]

    lstm_trans_kernel<<<dim3(NBATCH), dim3(64), 0, stream>>>(
        x, Wx, Wh, bias, Wd, bd, out);
}